// Round 1
// baseline (62.519 us; speedup 1.0000x reference)
//
#include <hip/hip_runtime.h>

#define BN_B 32
#define BN_N 65536
#define BLOCKS_PER_B 64
#define THREADS 256
// points per block = BN_N / BLOCKS_PER_B = 1024 -> 4 points/thread

// Per-point math shared by both passes.
// Loads 18 floats, computes hpd[6], gd, ihdd.
__device__ __forceinline__ void point_core(
    const float* __restrict__ r, const float* __restrict__ w,
    const float* __restrict__ J_p, const float* __restrict__ J_d,
    size_t p, float lam,
    float jpa[6], float jpb[6], float& c, float& cr0, float& cr1,
    float hpd[6], float& gd, float& ihdd)
{
    float2 wv = *(const float2*)(w + p * 2);
    float2 rv = *(const float2*)(r + p * 2);
    float2 jd = *(const float2*)(J_d + p * 2);
    float4 jp0 = *(const float4*)(J_p + p * 12);
    float4 jp1 = *(const float4*)(J_p + p * 12 + 4);
    float4 jp2 = *(const float4*)(J_p + p * 12 + 8);
    c = wv.x;
    float nl = wv.y;
    jpa[0] = jp0.x; jpa[1] = jp0.y; jpa[2] = jp0.z; jpa[3] = jp0.w; jpa[4] = jp1.x; jpa[5] = jp1.y;
    jpb[0] = jp1.z; jpb[1] = jp1.w; jpb[2] = jp2.x; jpb[3] = jp2.y; jpb[4] = jp2.z; jpb[5] = jp2.w;
    float cjd0 = c * jd.x, cjd1 = c * jd.y;
#pragma unroll
    for (int i = 0; i < 6; ++i) hpd[i] = jpa[i] * cjd0 + jpb[i] * cjd1;
    float hdd = jd.x * cjd0 + jd.y * cjd1;
    cr0 = c * rv.x; cr1 = c * rv.y;
    gd = jd.x * cr0 + jd.y * cr1;
    ihdd = 1.0f / (hdd + lam + nl + 1e-6f);
}

__global__ __launch_bounds__(THREADS) void k_reduce(
    const float* __restrict__ r, const float* __restrict__ w,
    const float* __restrict__ J_p, const float* __restrict__ J_d,
    const float* __restrict__ lmbda, float* __restrict__ partials)
{
    const int b = blockIdx.y;
    const int blk = blockIdx.x;
    const float lam = lmbda[0];

    float acc[27];
#pragma unroll
    for (int i = 0; i < 27; ++i) acc[i] = 0.0f;

    const int n0 = blk * (BN_N / BLOCKS_PER_B);
    const int n1 = n0 + (BN_N / BLOCKS_PER_B);
    const size_t baseP = (size_t)b * BN_N;

    for (int n = n0 + (int)threadIdx.x; n < n1; n += THREADS) {
        size_t p = baseP + n;
        float jpa[6], jpb[6], hpd[6];
        float c, cr0, cr1, gd, ihdd;
        point_core(r, w, J_p, J_d, p, lam, jpa, jpb, c, cr0, cr1, hpd, gd, ihdd);

        int t = 0;
#pragma unroll
        for (int i = 0; i < 6; ++i) {
            float ca = c * jpa[i];
            float cb = c * jpb[i];
            float hs = ihdd * hpd[i];
#pragma unroll
            for (int j = i; j < 6; ++j, ++t)
                acc[t] += ca * jpa[j] + cb * jpb[j] - hs * hpd[j];
            acc[21 + i] += jpa[i] * cr0 + jpb[i] * cr1 - hs * gd;
        }
    }

    // Wave-level reduce (64 lanes), then cross-wave via LDS.
#pragma unroll
    for (int i = 0; i < 27; ++i) {
        float v = acc[i];
#pragma unroll
        for (int off = 32; off > 0; off >>= 1) v += __shfl_down(v, off);
        acc[i] = v;
    }

    __shared__ float red[4][27];
    const int wave = threadIdx.x >> 6;
    const int lane = threadIdx.x & 63;
    if (lane == 0) {
#pragma unroll
        for (int i = 0; i < 27; ++i) red[wave][i] = acc[i];
    }
    __syncthreads();
    if (threadIdx.x < 27) {
        float s = red[0][threadIdx.x] + red[1][threadIdx.x] +
                  red[2][threadIdx.x] + red[3][threadIdx.x];
        partials[((size_t)b * BLOCKS_PER_B + blk) * 27 + threadIdx.x] = s;
    }
}

__global__ void k_solve(const float* __restrict__ partials,
                        const float* __restrict__ lmbda,
                        float* __restrict__ out)
{
    const int b = blockIdx.x;
    __shared__ float sum27[27];
    if (threadIdx.x < 27) {
        float s = 0.0f;
        for (int p = 0; p < BLOCKS_PER_B; ++p)
            s += partials[((size_t)b * BLOCKS_PER_B + p) * 27 + threadIdx.x];
        sum27[threadIdx.x] = s;
    }
    __syncthreads();
    if (threadIdx.x == 0) {
        const float lam = lmbda[0];
        float A[6][7];
        int t = 0;
        for (int i = 0; i < 6; ++i)
            for (int j = i; j < 6; ++j, ++t) { A[i][j] = sum27[t]; A[j][i] = sum27[t]; }
        for (int i = 0; i < 6; ++i) A[i][i] += lam + 0.001f;
        for (int i = 0; i < 6; ++i) A[i][6] = sum27[21 + i];

        // Gaussian elimination with partial pivoting
        for (int col = 0; col < 6; ++col) {
            int piv = col;
            float best = fabsf(A[col][col]);
            for (int rw = col + 1; rw < 6; ++rw) {
                float v = fabsf(A[rw][col]);
                if (v > best) { best = v; piv = rw; }
            }
            if (piv != col) {
                for (int j = 0; j < 7; ++j) {
                    float tmp = A[col][j]; A[col][j] = A[piv][j]; A[piv][j] = tmp;
                }
            }
            float inv = 1.0f / A[col][col];
            for (int rw = col + 1; rw < 6; ++rw) {
                float f = A[rw][col] * inv;
                for (int j = col; j < 7; ++j) A[rw][j] -= f * A[col][j];
            }
        }
        float x[6];
        for (int i = 5; i >= 0; --i) {
            float s = A[i][6];
            for (int j = i + 1; j < 6; ++j) s -= A[i][j] * x[j];
            x[i] = s / A[i][i];
        }
        for (int i = 0; i < 6; ++i) out[b * 6 + i] = x[i];
    }
}

__global__ __launch_bounds__(THREADS) void k_depth(
    const float* __restrict__ r, const float* __restrict__ w,
    const float* __restrict__ J_p, const float* __restrict__ J_d,
    const float* __restrict__ lmbda, const float* __restrict__ dp,
    float* __restrict__ out_depth)
{
    const int b = blockIdx.y;
    const int blk = blockIdx.x;
    const float lam = lmbda[0];
    float d0 = dp[b * 6 + 0], d1 = dp[b * 6 + 1], d2 = dp[b * 6 + 2];
    float d3 = dp[b * 6 + 3], d4 = dp[b * 6 + 4], d5 = dp[b * 6 + 5];

    const int n0 = blk * (BN_N / BLOCKS_PER_B);
    const int n1 = n0 + (BN_N / BLOCKS_PER_B);
    const size_t baseP = (size_t)b * BN_N;

    for (int n = n0 + (int)threadIdx.x; n < n1; n += THREADS) {
        size_t p = baseP + n;
        float jpa[6], jpb[6], hpd[6];
        float c, cr0, cr1, gd, ihdd;
        point_core(r, w, J_p, J_d, p, lam, jpa, jpb, c, cr0, cr1, hpd, gd, ihdd);
        float v = hpd[0] * d0 + hpd[1] * d1 + hpd[2] * d2 +
                  hpd[3] * d3 + hpd[4] * d4 + hpd[5] * d5;
        out_depth[p] = ihdd * (gd - v);
    }
}

extern "C" void kernel_launch(void* const* d_in, const int* in_sizes, int n_in,
                              void* d_out, int out_size, void* d_ws, size_t ws_size,
                              hipStream_t stream) {
    const float* r     = (const float*)d_in[0];
    const float* w     = (const float*)d_in[1];
    const float* J_p   = (const float*)d_in[2];
    const float* J_d   = (const float*)d_in[3];
    const float* lmbda = (const float*)d_in[4];
    float* out = (float*)d_out;
    float* partials = (float*)d_ws;  // [B][BLOCKS_PER_B][27] floats = 216 KiB

    dim3 grid(BLOCKS_PER_B, BN_B);
    k_reduce<<<grid, THREADS, 0, stream>>>(r, w, J_p, J_d, lmbda, partials);
    k_solve<<<dim3(BN_B), 32, 0, stream>>>(partials, lmbda, out);
    k_depth<<<grid, THREADS, 0, stream>>>(r, w, J_p, J_d, lmbda, out, out + 192);
}

// Round 2
// 51.592 us; speedup vs baseline: 1.2118x; 1.2118x over previous
//
#include <hip/hip_runtime.h>

#define BN_B 32
#define BN_N 65536
#define BLOCKS_PER_B 64
#define THREADS 256
// points per block = BN_N / BLOCKS_PER_B = 1024 -> 4 points/thread

typedef _Float16 half_t;
struct alignas(16) Half8 { half_t h[8]; };
union StateU { Half8 s; uint4 u; };

#define STATE_OFFSET (256 * 1024)                       // partials live below
#define STATE_BYTES ((size_t)BN_B * BN_N * 16)          // 33.55 MB
#define WS_NEEDED (STATE_OFFSET + STATE_BYTES)

// Per-point math shared by both passes. Loads 18 floats.
__device__ __forceinline__ void point_core(
    const float* __restrict__ r, const float* __restrict__ w,
    const float* __restrict__ J_p, const float* __restrict__ J_d,
    size_t p, float lam,
    float jpa[6], float jpb[6], float& c, float& cr0, float& cr1,
    float hpd[6], float& gd, float& ihdd)
{
    float2 wv = *(const float2*)(w + p * 2);
    float2 rv = *(const float2*)(r + p * 2);
    float2 jd = *(const float2*)(J_d + p * 2);
    float4 jp0 = *(const float4*)(J_p + p * 12);
    float4 jp1 = *(const float4*)(J_p + p * 12 + 4);
    float4 jp2 = *(const float4*)(J_p + p * 12 + 8);
    c = wv.x;
    float nl = wv.y;
    jpa[0] = jp0.x; jpa[1] = jp0.y; jpa[2] = jp0.z; jpa[3] = jp0.w; jpa[4] = jp1.x; jpa[5] = jp1.y;
    jpb[0] = jp1.z; jpb[1] = jp1.w; jpb[2] = jp2.x; jpb[3] = jp2.y; jpb[4] = jp2.z; jpb[5] = jp2.w;
    float cjd0 = c * jd.x, cjd1 = c * jd.y;
#pragma unroll
    for (int i = 0; i < 6; ++i) hpd[i] = jpa[i] * cjd0 + jpb[i] * cjd1;
    float hdd = jd.x * cjd0 + jd.y * cjd1;
    cr0 = c * rv.x; cr1 = c * rv.y;
    gd = jd.x * cr0 + jd.y * cr1;
    ihdd = 1.0f / (hdd + lam + nl + 1e-6f);
}

template <bool WRITE_STATE>
__global__ __launch_bounds__(THREADS) void k_reduce(
    const float* __restrict__ r, const float* __restrict__ w,
    const float* __restrict__ J_p, const float* __restrict__ J_d,
    const float* __restrict__ lmbda, float* __restrict__ partials,
    uint4* __restrict__ state)
{
    const int b = blockIdx.y;
    const int blk = blockIdx.x;
    const float lam = lmbda[0];

    float acc[27];
#pragma unroll
    for (int i = 0; i < 27; ++i) acc[i] = 0.0f;

    const int n0 = blk * (BN_N / BLOCKS_PER_B);
    const int n1 = n0 + (BN_N / BLOCKS_PER_B);
    const size_t baseP = (size_t)b * BN_N;

    for (int n = n0 + (int)threadIdx.x; n < n1; n += THREADS) {
        size_t p = baseP + n;
        float jpa[6], jpb[6], hpd[6];
        float c, cr0, cr1, gd, ihdd;
        point_core(r, w, J_p, J_d, p, lam, jpa, jpb, c, cr0, cr1, hpd, gd, ihdd);

        StateU su;
        int t = 0;
#pragma unroll
        for (int i = 0; i < 6; ++i) {
            float ca = c * jpa[i];
            float cb = c * jpb[i];
            float hs = ihdd * hpd[i];
#pragma unroll
            for (int j = i; j < 6; ++j, ++t)
                acc[t] += ca * jpa[j] + cb * jpb[j] - hs * hpd[j];
            acc[21 + i] += jpa[i] * cr0 + jpb[i] * cr1 - hs * gd;
            if (WRITE_STATE) su.s.h[i] = (half_t)hs;
        }
        if (WRITE_STATE) {
            su.s.h[6] = (half_t)(ihdd * gd);
            su.s.h[7] = (half_t)0.0f;
            state[p] = su.u;
        }
    }

    // Wave-level reduce (64 lanes), then cross-wave via LDS.
#pragma unroll
    for (int i = 0; i < 27; ++i) {
        float v = acc[i];
#pragma unroll
        for (int off = 32; off > 0; off >>= 1) v += __shfl_down(v, off);
        acc[i] = v;
    }

    __shared__ float red[4][27];
    const int wave = threadIdx.x >> 6;
    const int lane = threadIdx.x & 63;
    if (lane == 0) {
#pragma unroll
        for (int i = 0; i < 27; ++i) red[wave][i] = acc[i];
    }
    __syncthreads();
    if (threadIdx.x < 27) {
        float s = red[0][threadIdx.x] + red[1][threadIdx.x] +
                  red[2][threadIdx.x] + red[3][threadIdx.x];
        partials[((size_t)b * BLOCKS_PER_B + blk) * 27 + threadIdx.x] = s;
    }
}

__global__ void k_solve(const float* __restrict__ partials,
                        const float* __restrict__ lmbda,
                        float* __restrict__ out)
{
    const int b = blockIdx.x;
    __shared__ float sum27[27];
    if (threadIdx.x < 27) {
        float s = 0.0f;
        for (int p = 0; p < BLOCKS_PER_B; ++p)
            s += partials[((size_t)b * BLOCKS_PER_B + p) * 27 + threadIdx.x];
        sum27[threadIdx.x] = s;
    }
    __syncthreads();
    if (threadIdx.x == 0) {
        const float lam = lmbda[0];
        float A[6][7];
        int t = 0;
        for (int i = 0; i < 6; ++i)
            for (int j = i; j < 6; ++j, ++t) { A[i][j] = sum27[t]; A[j][i] = sum27[t]; }
        for (int i = 0; i < 6; ++i) A[i][i] += lam + 0.001f;
        for (int i = 0; i < 6; ++i) A[i][6] = sum27[21 + i];

        for (int col = 0; col < 6; ++col) {
            int piv = col;
            float best = fabsf(A[col][col]);
            for (int rw = col + 1; rw < 6; ++rw) {
                float v = fabsf(A[rw][col]);
                if (v > best) { best = v; piv = rw; }
            }
            if (piv != col) {
                for (int j = 0; j < 7; ++j) {
                    float tmp = A[col][j]; A[col][j] = A[piv][j]; A[piv][j] = tmp;
                }
            }
            float inv = 1.0f / A[col][col];
            for (int rw = col + 1; rw < 6; ++rw) {
                float f = A[rw][col] * inv;
                for (int j = col; j < 7; ++j) A[rw][j] -= f * A[col][j];
            }
        }
        float x[6];
        for (int i = 5; i >= 0; --i) {
            float s = A[i][6];
            for (int j = i + 1; j < 6; ++j) s -= A[i][j] * x[j];
            x[i] = s / A[i][i];
        }
        for (int i = 0; i < 6; ++i) out[b * 6 + i] = x[i];
    }
}

// Fast phase 2: read 16B/point of fp16 state instead of 72B of inputs.
__global__ __launch_bounds__(THREADS) void k_depth2(
    const uint4* __restrict__ state, const float* __restrict__ dp,
    float* __restrict__ out_depth)
{
    const int b = blockIdx.y;
    const int blk = blockIdx.x;
    float d[6];
#pragma unroll
    for (int i = 0; i < 6; ++i) d[i] = dp[b * 6 + i];

    const int n0 = blk * (BN_N / BLOCKS_PER_B);
    const int n1 = n0 + (BN_N / BLOCKS_PER_B);
    const size_t baseP = (size_t)b * BN_N;

    for (int n = n0 + (int)threadIdx.x; n < n1; n += THREADS) {
        size_t p = baseP + n;
        StateU su;
        su.u = state[p];
        float v = 0.0f;
#pragma unroll
        for (int i = 0; i < 6; ++i) v += (float)su.s.h[i] * d[i];
        out_depth[p] = (float)su.s.h[6] - v;
    }
}

// Fallback phase 2 (recompute from inputs) if d_ws is too small.
__global__ __launch_bounds__(THREADS) void k_depth(
    const float* __restrict__ r, const float* __restrict__ w,
    const float* __restrict__ J_p, const float* __restrict__ J_d,
    const float* __restrict__ lmbda, const float* __restrict__ dp,
    float* __restrict__ out_depth)
{
    const int b = blockIdx.y;
    const int blk = blockIdx.x;
    const float lam = lmbda[0];
    float d0 = dp[b * 6 + 0], d1 = dp[b * 6 + 1], d2 = dp[b * 6 + 2];
    float d3 = dp[b * 6 + 3], d4 = dp[b * 6 + 4], d5 = dp[b * 6 + 5];

    const int n0 = blk * (BN_N / BLOCKS_PER_B);
    const int n1 = n0 + (BN_N / BLOCKS_PER_B);
    const size_t baseP = (size_t)b * BN_N;

    for (int n = n0 + (int)threadIdx.x; n < n1; n += THREADS) {
        size_t p = baseP + n;
        float jpa[6], jpb[6], hpd[6];
        float c, cr0, cr1, gd, ihdd;
        point_core(r, w, J_p, J_d, p, lam, jpa, jpb, c, cr0, cr1, hpd, gd, ihdd);
        float v = hpd[0] * d0 + hpd[1] * d1 + hpd[2] * d2 +
                  hpd[3] * d3 + hpd[4] * d4 + hpd[5] * d5;
        out_depth[p] = ihdd * (gd - v);
    }
}

extern "C" void kernel_launch(void* const* d_in, const int* in_sizes, int n_in,
                              void* d_out, int out_size, void* d_ws, size_t ws_size,
                              hipStream_t stream) {
    const float* r     = (const float*)d_in[0];
    const float* w     = (const float*)d_in[1];
    const float* J_p   = (const float*)d_in[2];
    const float* J_d   = (const float*)d_in[3];
    const float* lmbda = (const float*)d_in[4];
    float* out = (float*)d_out;
    float* partials = (float*)d_ws;  // [B][BLOCKS_PER_B][27] floats = 216 KiB
    uint4* state = (uint4*)((char*)d_ws + STATE_OFFSET);

    dim3 grid(BLOCKS_PER_B, BN_B);
    if (ws_size >= WS_NEEDED) {
        k_reduce<true><<<grid, THREADS, 0, stream>>>(r, w, J_p, J_d, lmbda, partials, state);
        k_solve<<<dim3(BN_B), 32, 0, stream>>>(partials, lmbda, out);
        k_depth2<<<grid, THREADS, 0, stream>>>(state, out, out + 192);
    } else {
        k_reduce<false><<<grid, THREADS, 0, stream>>>(r, w, J_p, J_d, lmbda, partials, nullptr);
        k_solve<<<dim3(BN_B), 32, 0, stream>>>(partials, lmbda, out);
        k_depth<<<grid, THREADS, 0, stream>>>(r, w, J_p, J_d, lmbda, out, out + 192);
    }
}